// Round 13
// baseline (723.393 us; speedup 1.0000x reference)
//
#include <hip/hip_runtime.h>
#include <hip/hip_bf16.h>
#include <math.h>

// Decoder_62234076119175 — round 13: attn heads 0-15 overlapped with draft
// chunk h0=16 (ride-along blocks); wo GEMM split-K=3 (768 blocks, D2 in dead
// scores region). Fallback (ws<123MB) = round-10 schedule. Draft/top-k f32
// bit-identical.

typedef unsigned short u16;
typedef unsigned long long u64;
using bf16x8 = __attribute__((ext_vector_type(8))) short;
using f32x4  = __attribute__((ext_vector_type(4))) float;

#define NEGBIG -1e30f
#define QSCALE 0.08838834764831845f

__device__ __forceinline__ unsigned int fkey(float f) {
    unsigned int u = __float_as_uint(f);
    return (u & 0x80000000u) ? ~u : (u | 0x80000000u);
}

__device__ __forceinline__ u16 f2b(float f) {
    union { float f; unsigned u; } x; x.f = f;
    unsigned r = x.u + 0x7fffu + ((x.u >> 16) & 1u);  // RNE
    return (u16)(r >> 16);
}

__device__ __forceinline__ void gl_lds16(const u16* g, u16* l) {
    __builtin_amdgcn_global_load_lds(
        (__attribute__((address_space(1))) void*)(g),
        (__attribute__((address_space(3))) void*)(l), 16, 0, 0);
}

__device__ __forceinline__ void rope_table_calc(int row, int i,
    float* __restrict__ cosb, float* __restrict__ sinb)
{
    double inv = pow(10000.0, -((double)(2 * i)) / 128.0);
    double ang = (double)row * inv;
    cosb[row * 64 + i] = (float)cos(ang);
    sinb[row * 64 + i] = (float)sin(ang);
}

// ---------------- f32 [K][N] -> bf16 [N][K] transpose tile ------------------
__device__ __forceinline__ void transpose_tile(
    const float* __restrict__ in, u16* __restrict__ out, int Kdim, int N,
    int bx, int by)
{
    __shared__ u16 tile[64][66];
    int n0 = bx * 64, k0 = by * 64;
    int t = threadIdx.x;
#pragma unroll
    for (int u = 0; u < 16; ++u) {
        int e = u * 256 + t; int r = e >> 6, c = e & 63;
        tile[r][c] = f2b(in[(size_t)(k0 + r) * N + n0 + c]);
    }
    __syncthreads();
#pragma unroll
    for (int u = 0; u < 16; ++u) {
        int e = u * 256 + t; int r = e >> 6, c = e & 63;
        out[(size_t)(n0 + r) * Kdim + k0 + c] = tile[c][r];
    }
}

__global__ __launch_bounds__(256) void transpose_bf16_kernel(
    const float* __restrict__ in, u16* __restrict__ out, int Kdim, int N)
{
    transpose_tile(in, out, Kdim, N, blockIdx.x, blockIdx.y);
}

// ---------------- small-path kernels (round-10 fallback) --------------------
__global__ __launch_bounds__(256) void init_kernel(
    const float* __restrict__ hs, u16* __restrict__ hs_bf,
    float* __restrict__ cosb, float* __restrict__ sinb)
{
    int bx = blockIdx.x, t = threadIdx.x;
    if (bx < 4096) {
        int i = bx * 256 + t;
        float4 v = ((const float4*)hs)[i];
        u16 o[4] = {f2b(v.x), f2b(v.y), f2b(v.z), f2b(v.w)};
        ((uint2*)hs_bf)[i] = *(const uint2*)o;
    } else {
        rope_table_calc((bx - 4096) * 4 + (t >> 6), t & 63, cosb, sinb);
    }
}

__global__ __launch_bounds__(256) void transpose_qkvw_kernel(
    const float* __restrict__ wq, const float* __restrict__ wk, const float* __restrict__ wv,
    u16* __restrict__ wqT, u16* __restrict__ wkT, u16* __restrict__ wvT)
{
    int bx = blockIdx.x;
    const float* in; u16* outp; int N;
    if (bx < 64)      { in = wq; outp = wqT; N = 4096; }
    else if (bx < 80) { in = wk; outp = wkT; N = 1024; bx -= 64; }
    else              { in = wv; outp = wvT; N = 1024; bx -= 80; }
    transpose_tile(in, outp, 4096, N, bx, blockIdx.y);
}

__global__ __launch_bounds__(128) void rope_pack2_kernel(
    const float* __restrict__ qb, const float* __restrict__ kb,
    const float* __restrict__ cosb, const float* __restrict__ sinb,
    u16* __restrict__ qr, u16* __restrict__ kr)
{
    int s = blockIdx.x, h = blockIdx.y, d = threadIdx.x;
    const float* src; u16* dst; int W; float scale;
    if (h < 32) { src = qb; dst = qr; W = 4096; scale = QSCALE; }
    else        { h -= 32; src = kb; dst = kr; W = 1024; scale = 1.0f; }
    float x  = src[(size_t)s * W + h * 128 + d];
    float x2 = src[(size_t)s * W + h * 128 + (d ^ 64)];
    float cs = cosb[s * 64 + (d & 63)];
    float sn = sinb[s * 64 + (d & 63)];
    float rot = (d < 64) ? -x2 : x2;
    dst[((size_t)h * 1024 + s) * 128 + d] = f2b((x * cs + rot * sn) * scale);
}

__global__ __launch_bounds__(256) void lr_kernel(
    const float* __restrict__ hs, const float* __restrict__ mixq, const float* __restrict__ mixk,
    float* __restrict__ lrq, float* __restrict__ lrk)
{
    __shared__ float row[4096];
    __shared__ float part[2][32][4];
    int m = blockIdx.x, t = threadIdx.x;
#pragma unroll
    for (int u = 0; u < 4; ++u)
        ((float4*)row)[t + u * 256] = ((const float4*)(hs + (size_t)m * 4096))[t + u * 256];
    __syncthreads();
    int r = t & 31, which = (t >> 5) & 1, quarter = t >> 6;
    const float* mix = which ? mixk : mixq;
    float acc = 0.f;
    int kbase = quarter * 1024;
#pragma unroll 8
    for (int kk = 0; kk < 1024; ++kk)
        acc = fmaf(row[kbase + kk], mix[(size_t)(kbase + kk) * 32 + r], acc);
    part[which][r][quarter] = acc;
    __syncthreads();
    if (t < 64) {
        int r2 = t & 31, w2 = t >> 5;
        float s = part[w2][r2][0] + part[w2][r2][1] + part[w2][r2][2] + part[w2][r2][3];
        (w2 ? lrk : lrq)[(size_t)m * 32 + r2] = s;
    }
}

__global__ __launch_bounds__(128) void ppos2_kernel(
    const float* __restrict__ lrq, const float* __restrict__ lrk,
    const float* __restrict__ qpos, const float* __restrict__ kpos,
    float* __restrict__ pq, float* __restrict__ pk)
{
    int h = blockIdx.x, by = blockIdx.y, d = threadIdx.x;
    const float* lr; const float* pos; float* outp; int m;
    if (by < 512) { m = 512 + by; lr = lrq; pos = qpos; outp = pq; }
    else          { m = by - 512; lr = lrk; pos = kpos; outp = pk; }
    __shared__ float lrs[32];
    if (d < 32) lrs[d] = lr[(size_t)m * 32 + d];
    __syncthreads();
    const float* base = pos + ((size_t)(m * 32 + h) * 32) * 128 + d;
    float acc = 0.f;
#pragma unroll
    for (int r = 0; r < 32; ++r)
        acc = fmaf(lrs[r], base[(size_t)r * 128], acc);
    outp[((size_t)h * 1024 + m) * 128 + d] = acc;
}

// ------------- big path: fused init (conv + tables + lr + w transposes) ----
__global__ __launch_bounds__(256) void init_fused_kernel(
    const float* __restrict__ hs, u16* __restrict__ hs_bf,
    float* __restrict__ cosb, float* __restrict__ sinb,
    const float* __restrict__ mixq, const float* __restrict__ mixk,
    float* __restrict__ lrq, float* __restrict__ lrk,
    const float* __restrict__ wq, const float* __restrict__ wk, const float* __restrict__ wv,
    u16* __restrict__ wqT, u16* __restrict__ wkT, u16* __restrict__ wvT)
{
    __shared__ float row[4096];
    __shared__ float part[2][32][4];
    int bx = blockIdx.x, t = threadIdx.x;
    if (bx < 4096) {
        int i = bx * 256 + t;
        float4 v = ((const float4*)hs)[i];
        u16 o[4] = {f2b(v.x), f2b(v.y), f2b(v.z), f2b(v.w)};
        ((uint2*)hs_bf)[i] = *(const uint2*)o;
    } else if (bx < 4352) {
        rope_table_calc((bx - 4096) * 4 + (t >> 6), t & 63, cosb, sinb);
    } else if (bx < 5376) {
        int m = bx - 4352;
#pragma unroll
        for (int u = 0; u < 4; ++u)
            ((float4*)row)[t + u * 256] = ((const float4*)(hs + (size_t)m * 4096))[t + u * 256];
        __syncthreads();
        int r = t & 31, which = (t >> 5) & 1, quarter = t >> 6;
        const float* mix = which ? mixk : mixq;
        float acc = 0.f;
        int kbase = quarter * 1024;
#pragma unroll 8
        for (int kk = 0; kk < 1024; ++kk)
            acc = fmaf(row[kbase + kk], mix[(size_t)(kbase + kk) * 32 + r], acc);
        part[which][r][quarter] = acc;
        __syncthreads();
        if (t < 64) {
            int r2 = t & 31, w2 = t >> 5;
            float s = part[w2][r2][0] + part[w2][r2][1] + part[w2][r2][2] + part[w2][r2][3];
            (w2 ? lrk : lrq)[(size_t)m * 32 + r2] = s;
        }
    } else {
        int idx = bx - 5376;
        int bxT = idx % 96, byT = idx / 96;
        const float* in; u16* outp; int N;
        if (bxT < 64)      { in = wq; outp = wqT; N = 4096; }
        else if (bxT < 80) { in = wk; outp = wkT; N = 1024; bxT -= 64; }
        else               { in = wv; outp = wvT; N = 1024; bxT -= 80; }
        transpose_tile(in, outp, 4096, N, bxT, byT);
    }
}

// ---------------- bf16 MFMA GEMM panel (m97 structure) ----------------------
__device__ __forceinline__ void gemm_bf16_panel(
    const u16* __restrict__ Ap, const u16* __restrict__ Bp,
    float* __restrict__ Cp, int Kdim, int kbase, int klen, int Cst)
{
    __shared__ u16 As[128 * 32];
    __shared__ u16 Bs[128 * 32];
    const int t = threadIdx.x;
    const int wave = t >> 6, lane = t & 63;
    const int wr = wave >> 1, wc = wave & 1;
    const int fr = lane & 15, fq = lane >> 4;

    f32x4 acc[4][4];
#pragma unroll
    for (int m = 0; m < 4; ++m)
#pragma unroll
        for (int n = 0; n < 4; ++n) acc[m][n] = 0.f;

    const int srow = 32 * wave + (lane >> 2);
    const int skc = (lane & 3) * 8;
    const u16* aS = Ap + (size_t)srow * Kdim + kbase + skc;
    const u16* bS = Bp + (size_t)srow * Kdim + kbase + skc;
    u16* aD0 = As + 1024 * wave;  u16* aD1 = aD0 + 512;
    u16* bD0 = Bs + 1024 * wave;  u16* bD1 = bD0 + 512;

    const int aoff = (wr * 64 + fr) * 32 + fq * 8;
    const int boff = (wc * 64 + fr) * 32 + fq * 8;

    for (int k0 = 0; k0 < klen; k0 += 32) {
        __syncthreads();
        gl_lds16(aS + k0, aD0);
        gl_lds16(aS + (size_t)16 * Kdim + k0, aD1);
        gl_lds16(bS + k0, bD0);
        gl_lds16(bS + (size_t)16 * Kdim + k0, bD1);
        __syncthreads();

        bf16x8 af[4], bfr[4];
#pragma unroll
        for (int m = 0; m < 4; ++m) af[m] = *(const bf16x8*)(As + aoff + m * 512);
#pragma unroll
        for (int n = 0; n < 4; ++n) bfr[n] = *(const bf16x8*)(Bs + boff + n * 512);
#pragma unroll
        for (int m = 0; m < 4; ++m)
#pragma unroll
            for (int n = 0; n < 4; ++n)
                acc[m][n] = __builtin_amdgcn_mfma_f32_16x16x32_bf16(af[m], bfr[n], acc[m][n], 0, 0, 0);
    }

    float* Cb = Cp + (size_t)(wr * 64 + fq * 4) * Cst + wc * 64 + fr;
#pragma unroll
    for (int m = 0; m < 4; ++m)
#pragma unroll
        for (int j = 0; j < 4; ++j)
#pragma unroll
            for (int n = 0; n < 4; ++n)
                Cb[(size_t)(m * 16 + j) * Cst + n * 16] = acc[m][n][j];
}

// small-path GEMM wrappers
__global__ __launch_bounds__(256) void gemm_qkv_bf16_kernel(
    const u16* __restrict__ hs_bf, const u16* __restrict__ wqT,
    const u16* __restrict__ wkT, const u16* __restrict__ wvT,
    float* __restrict__ q, float* __restrict__ k, float* __restrict__ v)
{
    int bn = blockIdx.x, bm = blockIdx.y;
    const u16* Bsel; float* Csel; int Ncols;
    if (bn < 32)      { Bsel = wqT; Csel = q; Ncols = 4096; }
    else if (bn < 40) { Bsel = wkT; Csel = k; Ncols = 1024; bn -= 32; }
    else              { Bsel = wvT; Csel = v; Ncols = 1024; bn -= 40; }
    gemm_bf16_panel(hs_bf + (size_t)bm * 128 * 4096, Bsel + (size_t)bn * 128 * 4096,
                    Csel + (size_t)bm * 128 * Ncols + bn * 128, 4096, 0, 4096, Ncols);
}

__global__ __launch_bounds__(256) void gemm_wo_bf16_kernel(
    const u16* __restrict__ attn_bf, const u16* __restrict__ woT, float* __restrict__ out)
{
    int bn = blockIdx.x, bm = blockIdx.y;
    gemm_bf16_panel(attn_bf + (size_t)bm * 128 * 4096, woT + (size_t)bn * 128 * 4096,
                    out + (size_t)bm * 128 * 4096 + bn * 128, 4096, 0, 4096, 4096);
}

// ------------- big path: mega kernel — qkv GEMM + ppos co-resident ----------
__global__ __launch_bounds__(256) void qkv_ppos_kernel(
    const u16* __restrict__ hs_bf, const u16* __restrict__ wqT,
    const u16* __restrict__ wkT, const u16* __restrict__ wvT,
    float* __restrict__ C,
    const float* __restrict__ lrq, const float* __restrict__ lrk,
    const float* __restrict__ qpos, const float* __restrict__ kpos,
    float* __restrict__ pq, float* __restrict__ pk)
{
    int bx = blockIdx.x, t = threadIdx.x;
    if (bx < 384) {
        int bn = bx % 48, bm = bx / 48;
        const u16* Bsel; int bnrow;
        if (bn < 32)      { Bsel = wqT; bnrow = bn; }
        else if (bn < 40) { Bsel = wkT; bnrow = bn - 32; }
        else              { Bsel = wvT; bnrow = bn - 40; }
        gemm_bf16_panel(hs_bf + (size_t)bm * 128 * 4096, Bsel + (size_t)bnrow * 128 * 4096,
                        C + (size_t)bm * 128 * 6144 + bn * 128, 4096, 0, 4096, 6144);
    } else {
        int idx = bx - 384;
        int bp = idx >> 5, h = idx & 31;
        int sub = t >> 7, d = t & 127;
        int by = bp * 2 + sub;
        const float* lr; const float* pos; float* outp; int m;
        if (by < 512) { m = 512 + by; lr = lrq; pos = qpos; outp = pq; }
        else          { m = by - 512; lr = lrk; pos = kpos; outp = pk; }
        __shared__ float lrs[2][32];
        if (d < 32) lrs[sub][d] = lr[(size_t)m * 32 + d];
        __syncthreads();
        const float* base = pos + ((size_t)(m * 32 + h) * 32) * 128 + d;
        float acc = 0.f;
#pragma unroll
        for (int r = 0; r < 32; ++r)
            acc = fmaf(lrs[sub][r], base[(size_t)r * 128], acc);
        outp[((size_t)h * 1024 + m) * 128 + d] = acc;
    }
}

// ------------- reduce: rope pack (q,k) item + v transpose -------------------
__device__ __forceinline__ void reduce_rope_item(
    const float* __restrict__ C,
    const float* __restrict__ cosb, const float* __restrict__ sinb,
    u16* __restrict__ qr, u16* __restrict__ kr, int bx)
{
    int t = threadIdx.x;
    int sp = bx & 511, h40 = bx >> 9;
    int s = sp * 2 + (t >> 7), d = t & 127;
    int col; u16* dst; float scale;
    if (h40 < 32) { col = h40 * 128 + d; dst = qr + ((size_t)h40 * 1024 + s) * 128 + d; scale = QSCALE; }
    else { col = 4096 + (h40 - 32) * 128 + d; dst = kr + ((size_t)(h40 - 32) * 1024 + s) * 128 + d; scale = 1.0f; }
    int colp = col ^ 64;
    float x  = C[(size_t)s * 6144 + col];
    float x2 = C[(size_t)s * 6144 + colp];
    float cs = cosb[s * 64 + (d & 63)];
    float sn = sinb[s * 64 + (d & 63)];
    float rot = (d < 64) ? -x2 : x2;
    *dst = f2b((x * cs + rot * sn) * scale);
}

__device__ __forceinline__ void v_transpose_dev(
    const float* __restrict__ C, u16* __restrict__ vT, int idx)
{
    __shared__ u16 vtile[64][66];
    int bxT = idx & 15, byT = idx >> 4;
    int n0 = bxT * 64, k0 = byT * 64;
    int t = threadIdx.x;
#pragma unroll
    for (int u = 0; u < 16; ++u) {
        int e = u * 256 + t; int r = e >> 6, c = e & 63;
        vtile[r][c] = f2b(C[(size_t)(k0 + r) * 6144 + 5120 + n0 + c]);
    }
    __syncthreads();
#pragma unroll
    for (int u = 0; u < 16; ++u) {
        int e = u * 256 + t; int r = e >> 6, c = e & 63;
        vT[(size_t)(n0 + r) * 1024 + k0 + c] = vtile[c][r];
    }
}

// ---------------- draft tile compute (f32 exact, 128x64) --------------------
__device__ __forceinline__ void draft_tile_compute(
    const float* __restrict__ pq, const float* __restrict__ pk,
    float* __restrict__ scores, int h0, int idx, int hh)
{
    int bm, bc;
    if (idx < 10)      { bm = 4; bc = idx; }
    else if (idx < 22) { bm = 5; bc = idx - 10; }
    else if (idx < 36) { bm = 6; bc = idx - 22; }
    else               { bm = 7; bc = idx - 36; }

    const float* A  = pq + ((size_t)(h0 + hh) * 1024 + bm * 128) * 128;
    const float* BT = pk + ((size_t)(h0 + hh) * 1024 + bc * 64) * 128;
    float* Cs = scores + ((size_t)hh * 512 + (bm - 4) * 128) * 1024 + bc * 64;

    __shared__ float As[8][128];
    __shared__ float Bs[8][64];
    const int t = threadIdx.x;
    const int tx = t & 15, ty = (t >> 4) & 15;

    float acc[8][4];
#pragma unroll
    for (int u = 0; u < 8; ++u)
#pragma unroll
        for (int w = 0; w < 4; ++w) acc[u][w] = 0.f;

    const int ai = t >> 1, ah = (t & 1) * 4;
    const int bi = t >> 2, bh = (t & 3) * 2;
    const float* Ap = A + (size_t)ai * 128 + ah;
    const float* Bp = BT + (size_t)bi * 128 + bh;

    for (int k0 = 0; k0 < 128; k0 += 8) {
        float4 av = *(const float4*)(Ap + k0);
        float2 bv = *(const float2*)(Bp + k0);
        __syncthreads();
        As[ah + 0][ai] = av.x; As[ah + 1][ai] = av.y;
        As[ah + 2][ai] = av.z; As[ah + 3][ai] = av.w;
        Bs[bh][bi] = bv.x; Bs[bh + 1][bi] = bv.y;
        __syncthreads();
#pragma unroll
        for (int kk = 0; kk < 8; ++kk) {
            float4 a0 = *(const float4*)(&As[kk][ty * 4]);
            float4 a1 = *(const float4*)(&As[kk][64 + ty * 4]);
            float4 b0 = *(const float4*)(&Bs[kk][tx * 4]);
            float aa[8] = {a0.x, a0.y, a0.z, a0.w, a1.x, a1.y, a1.z, a1.w};
#pragma unroll
            for (int u = 0; u < 8; ++u) {
                acc[u][0] = fmaf(aa[u], b0.x, acc[u][0]);
                acc[u][1] = fmaf(aa[u], b0.y, acc[u][1]);
                acc[u][2] = fmaf(aa[u], b0.z, acc[u][2]);
                acc[u][3] = fmaf(aa[u], b0.w, acc[u][3]);
            }
        }
    }
#pragma unroll
    for (int u = 0; u < 8; ++u) {
        int row = (u < 4) ? (ty * 4 + u) : (64 + ty * 4 + (u - 4));
        *(float4*)(Cs + (size_t)row * 1024 + tx * 4)
            = make_float4(acc[u][0], acc[u][1], acc[u][2], acc[u][3]);
    }
}

__global__ __launch_bounds__(256) void draft_gemm_kernel(
    const float* __restrict__ pq, const float* __restrict__ pk,
    float* __restrict__ scores, int h0)
{
    draft_tile_compute(pq, pk, scores, h0, blockIdx.x, blockIdx.y);
}

// ---------------- attention block compute (swapped QK^T, KVBLK=64) ----------
#define ATTN_KP 136
#define ATTN_VP 72

__device__ __forceinline__ void attn_block_compute(
    const u16* __restrict__ qr, const u16* __restrict__ kr,
    const u16* __restrict__ vT,
    const unsigned long long* __restrict__ mask,
    u16* __restrict__ attn, int bxq, int h)
{
    int qt = (bxq & 1) ? (bxq >> 1) : (15 - (bxq >> 1));
    int kvh = h >> 2;
    int q0 = qt * 64;
    int t = threadIdx.x;
    int wave = t >> 6, lane = t & 63;
    int fr = lane & 15, fq = lane >> 4;
    int qrow = q0 + wave * 16 + fr;

    __shared__ u16 Ks[64 * ATTN_KP];
    __shared__ u16 Vs[128 * ATTN_VP];

    bf16x8 qf[4];
    const u16* qbase = qr + ((size_t)h * 1024 + qrow) * 128 + fq * 8;
#pragma unroll
    for (int kc = 0; kc < 4; ++kc)
        qf[kc] = *(const bf16x8*)(qbase + kc * 32);

    float m_run = -3.0e38f, l_run = 0.f;
    f32x4 accO[8];
#pragma unroll
    for (int m2 = 0; m2 < 8; ++m2) accO[m2] = 0.f;

    const unsigned long long* mrow = mask + ((size_t)h * 1024 + qrow) * 16;
    const bool use_mask = (qrow >= 512);
    const u16* kgh = kr + (size_t)kvh * 1024 * 128;
    const u16* vgh = vT + (size_t)kvh * 128 * 1024;

    int ntiles = qt + 1;
    for (int c = 0; c < ntiles; ++c) {
        int kv0 = c * 64;
        __syncthreads();
#pragma unroll
        for (int u = 0; u < 4; ++u) {
            int e = t + u * 256;
            int row = e >> 4, bc2 = (e & 15) * 8;
            uint4 d4 = *(const uint4*)(kgh + ((size_t)(kv0 + row)) * 128 + bc2);
            *(uint4*)(&Ks[row * ATTN_KP + bc2]) = d4;
        }
#pragma unroll
        for (int u = 0; u < 4; ++u) {
            int e = t + u * 256;
            int row = e >> 3, bc2 = (e & 7) * 8;
            uint4 d4 = *(const uint4*)(vgh + (size_t)row * 1024 + kv0 + bc2);
            *(uint4*)(&Vs[row * ATTN_VP + bc2]) = d4;
        }
        __syncthreads();

        f32x4 accS[4];
        accS[0] = 0.f; accS[1] = 0.f; accS[2] = 0.f; accS[3] = 0.f;
#pragma unroll
        for (int t2 = 0; t2 < 4; ++t2)
#pragma unroll
            for (int kc = 0; kc < 4; ++kc) {
                bf16x8 kf = *(const bf16x8*)(&Ks[(t2 * 16 + fr) * ATTN_KP + kc * 32 + fq * 8]);
                accS[t2] = __builtin_amdgcn_mfma_f32_16x16x32_bf16(kf, qf[kc], accS[t2], 0, 0, 0);
            }

        unsigned long long mw = use_mask ? mrow[c] : ~0ull;
        float p[4][4];
        float tmax = -3.0e38f;
#pragma unroll
        for (int t2 = 0; t2 < 4; ++t2)
#pragma unroll
            for (int j = 0; j < 4; ++j) {
                int kvi = (t2 << 4) + (fq << 2) + j;
                bool ok = ((mw >> kvi) & 1ull) && (kv0 + kvi <= qrow);
                float s = ok ? accS[t2][j] : -3.0e38f;
                p[t2][j] = s;
                tmax = fmaxf(tmax, s);
            }
        tmax = fmaxf(tmax, __shfl_xor(tmax, 16));
        tmax = fmaxf(tmax, __shfl_xor(tmax, 32));
        float m_new = fmaxf(m_run, tmax);
        float sf = __expf(m_run - m_new);
        float psum = 0.f;
#pragma unroll
        for (int t2 = 0; t2 < 4; ++t2)
#pragma unroll
            for (int j = 0; j < 4; ++j) {
                float e = (p[t2][j] > -1.0e38f) ? __expf(p[t2][j] - m_new) : 0.f;
                p[t2][j] = e;
                psum += e;
            }
        psum += __shfl_xor(psum, 16);
        psum += __shfl_xor(psum, 32);
        l_run = l_run * sf + psum;
        m_run = m_new;

#pragma unroll
        for (int m2 = 0; m2 < 8; ++m2) accO[m2] *= sf;

        union { uint4 u; bf16x8 b; } pc[2];
        int srcA = fr + ((fq & 1) << 5);
        int srcB = srcA + 16;
        bool hi = (fq & 2) != 0;
#pragma unroll
        for (int half = 0; half < 2; ++half) {
            unsigned W0, W1, W2, W3;
            asm("v_cvt_pk_bf16_f32 %0, %1, %2" : "=v"(W0) : "v"(p[2 * half][0]),     "v"(p[2 * half][1]));
            asm("v_cvt_pk_bf16_f32 %0, %1, %2" : "=v"(W1) : "v"(p[2 * half][2]),     "v"(p[2 * half][3]));
            asm("v_cvt_pk_bf16_f32 %0, %1, %2" : "=v"(W2) : "v"(p[2 * half + 1][0]), "v"(p[2 * half + 1][1]));
            asm("v_cvt_pk_bf16_f32 %0, %1, %2" : "=v"(W3) : "v"(p[2 * half + 1][2]), "v"(p[2 * half + 1][3]));
            unsigned a0 = __shfl(W0, srcA), a1 = __shfl(W1, srcA);
            unsigned a2 = __shfl(W2, srcA), a3 = __shfl(W3, srcA);
            unsigned b0 = __shfl(W0, srcB), b1 = __shfl(W1, srcB);
            unsigned b2 = __shfl(W2, srcB), b3 = __shfl(W3, srcB);
            pc[half].u.x = hi ? a2 : a0;
            pc[half].u.y = hi ? a3 : a1;
            pc[half].u.z = hi ? b2 : b0;
            pc[half].u.w = hi ? b3 : b1;
        }

#pragma unroll
        for (int m2 = 0; m2 < 8; ++m2) {
            bf16x8 vf0 = *(const bf16x8*)(&Vs[(m2 * 16 + fr) * ATTN_VP + fq * 8]);
            accO[m2] = __builtin_amdgcn_mfma_f32_16x16x32_bf16(vf0, pc[0].b, accO[m2], 0, 0, 0);
            bf16x8 vf1 = *(const bf16x8*)(&Vs[(m2 * 16 + fr) * ATTN_VP + 32 + fq * 8]);
            accO[m2] = __builtin_amdgcn_mfma_f32_16x16x32_bf16(vf1, pc[1].b, accO[m2], 0, 0, 0);
        }
    }

    float il = 1.0f / l_run;
    u16* obase = attn + (size_t)qrow * 4096 + h * 128 + fq * 4;
#pragma unroll
    for (int m2 = 0; m2 < 8; ++m2) {
        uint2 st;
        st.x = (unsigned)f2b(accO[m2][0] * il) | ((unsigned)f2b(accO[m2][1] * il) << 16);
        st.y = (unsigned)f2b(accO[m2][2] * il) | ((unsigned)f2b(accO[m2][3] * il) << 16);
        *(uint2*)(obase + m2 * 16) = st;
    }
}

__global__ __launch_bounds__(256) void attn_mfma_kernel(
    const u16* __restrict__ qr, const u16* __restrict__ kr,
    const u16* __restrict__ vT,
    const unsigned long long* __restrict__ mask,
    u16* __restrict__ attn, int hbase)
{
    attn_block_compute(qr, kr, vT, mask, attn, blockIdx.x, hbase + blockIdx.y);
}

// chunk 0: draft(h0=0) + reduce_rope + v-transpose riding along
__global__ __launch_bounds__(256) void draft0_fused_kernel(
    const float* __restrict__ pq, const float* __restrict__ pk,
    float* __restrict__ scores, const float* __restrict__ C,
    const float* __restrict__ cosb, const float* __restrict__ sinb,
    u16* __restrict__ qr, u16* __restrict__ kr, u16* __restrict__ vT)
{
    int bx = blockIdx.x;
    if (bx < 416) draft_tile_compute(pq, pk, scores, 0, bx % 52, bx / 52);
    else if (bx < 416 + 20480) reduce_rope_item(C, cosb, sinb, qr, kr, bx - 416);
    else v_transpose_dev(C, vT, bx - 416 - 20480);
}

// chunk 1: draft(h0=8) + wo transpose riding along
__global__ __launch_bounds__(256) void draft1_fused_kernel(
    const float* __restrict__ pq, const float* __restrict__ pk,
    float* __restrict__ scores, const float* __restrict__ wo, u16* __restrict__ woT)
{
    int bx = blockIdx.x;
    if (bx < 416) draft_tile_compute(pq, pk, scores, 8, bx % 52, bx / 52);
    else { int i = bx - 416; transpose_tile(wo, woT, 4096, 4096, i & 63, i >> 6); }
}

// chunk 2: draft(h0=16) + attention heads 0-15 riding along
__global__ __launch_bounds__(256) void draft2_attn_kernel(
    const float* __restrict__ pq, const float* __restrict__ pk,
    float* __restrict__ scores,
    const u16* __restrict__ qr, const u16* __restrict__ kr,
    const u16* __restrict__ vT, const unsigned long long* __restrict__ mask,
    u16* __restrict__ attn)
{
    int bx = blockIdx.x;
    if (bx < 416) draft_tile_compute(pq, pk, scores, 16, bx % 52, bx / 52);
    else {
        int i = bx - 416;                  // 256 blocks: 16 qt x 16 heads
        attn_block_compute(qr, kr, vT, mask, attn, i & 15, i >> 4);
    }
}

// ---------------- exact top-512 radix select (q>=512), float4 reads --------
__global__ __launch_bounds__(256) void topk_select_kernel(
    const float* __restrict__ scores, int h0,
    unsigned long long* __restrict__ mask)
{
    int qt = blockIdx.x, hh = blockIdx.y;
    int h = h0 + hh;
    int t = threadIdx.x;
    const int i = t >> 4, jj = t & 15;
    const int lrow = qt * 16 + i;
    const int qrow = 512 + lrow;

    const float* src = scores + ((size_t)hh * 512 + lrow) * 1024;

    unsigned int vals[64];
#pragma unroll
    for (int g = 0; g < 16; ++g) {
        float4 v = *(const float4*)(src + g * 64 + jj * 4);
        int col = g * 64 + jj * 4;
        vals[g * 4 + 0] = fkey((col + 0) <= qrow ? v.x : NEGBIG);
        vals[g * 4 + 1] = fkey((col + 1) <= qrow ? v.y : NEGBIG);
        vals[g * 4 + 2] = fkey((col + 2) <= qrow ? v.z : NEGBIG);
        vals[g * 4 + 3] = fkey((col + 3) <= qrow ? v.w : NEGBIG);
    }

    unsigned int p = 0u;
    int kth = 512;
    for (int b = 31; b >= 0; --b) {
        unsigned int bit = 1u << b;
        unsigned int himask = (b == 31) ? 0u : (0xFFFFFFFFu << (b + 1));
        int cnt = 0;
#pragma unroll
        for (int n = 0; n < 64; ++n)
            cnt += (int)((((vals[n] ^ p) & himask) == 0u) && ((vals[n] & bit) != 0u));
        cnt += __shfl_xor(cnt, 1);
        cnt += __shfl_xor(cnt, 2);
        cnt += __shfl_xor(cnt, 4);
        cnt += __shfl_xor(cnt, 8);
        if (cnt >= kth) p |= bit; else kth -= cnt;
    }

    unsigned long long wpart[16];
#pragma unroll
    for (int w = 0; w < 16; ++w) wpart[w] = 0ull;
#pragma unroll
    for (int g = 0; g < 16; ++g)
#pragma unroll
        for (int e = 0; e < 4; ++e)
            wpart[g] |= ((unsigned long long)(vals[g * 4 + e] >= p)) << (4 * jj + e);
#pragma unroll
    for (int s = 1; s < 16; s <<= 1) {
#pragma unroll
        for (int w = 0; w < 16; ++w)
            wpart[w] |= __shfl_xor(wpart[w], s);
    }
    mask[((size_t)h * 1024 + qrow) * 16 + jj] = wpart[jj];
}

// big path: split-K=3 wo GEMM (k splits 1376/1376/1344)
__global__ __launch_bounds__(256) void gemm_wo_sk3_kernel(
    const u16* __restrict__ attn_bf, const u16* __restrict__ woT,
    float* __restrict__ D0, float* __restrict__ D1, float* __restrict__ D2)
{
    int bn = blockIdx.x, bm = blockIdx.y, g = blockIdx.z;
    float* C = (g == 0) ? D0 : (g == 1) ? D1 : D2;
    int kbase = (g == 0) ? 0 : (g == 1) ? 1376 : 2752;
    int klen  = (g == 2) ? 1344 : 1376;
    gemm_bf16_panel(attn_bf + (size_t)bm * 128 * 4096, woT + (size_t)bn * 128 * 4096,
                    C + (size_t)bm * 128 * 4096 + bn * 128, 4096, kbase, klen, 4096);
}

__global__ __launch_bounds__(256) void reduce_out3_kernel(
    const float* __restrict__ D0, const float* __restrict__ D1,
    const float* __restrict__ D2, float* __restrict__ out)
{
    int i = blockIdx.x * 256 + threadIdx.x;
    float4 a = ((const float4*)D0)[i];
    float4 b = ((const float4*)D1)[i];
    float4 c = ((const float4*)D2)[i];
    ((float4*)out)[i] = make_float4(a.x + b.x + c.x, a.y + b.y + c.y,
                                    a.z + b.z + c.z, a.w + b.w + c.w);
}

extern "C" void kernel_launch(void* const* d_in, const int* in_sizes, int n_in,
                              void* d_out, int out_size, void* d_ws, size_t ws_size,
                              hipStream_t stream)
{
    (void)in_sizes; (void)n_in; (void)out_size;
    const float* hs   = (const float*)d_in[0];
    const float* wq   = (const float*)d_in[1];
    const float* wk   = (const float*)d_in[2];
    const float* wv   = (const float*)d_in[3];
    const float* wo   = (const float*)d_in[4];
    const float* mixq = (const float*)d_in[5];
    const float* mixk = (const float*)d_in[6];
    const float* qpos = (const float*)d_in[7];
    const float* kpos = (const float*)d_in[8];
    float* out = (float*)d_out;
    char* B = (char*)d_ws;
    const size_t MB = 1ull << 20;

    if (ws_size >= 123 * MB) {
        // ---- big path, compact layout (high-water ~121 MB) ----
        u16* hs_bf = (u16*)(B);                 // 0-8, later attn_bf
        u16* wkT   = (u16*)(B + 8 * MB);
        u16* wvT   = (u16*)(B + 16 * MB);
        u16* wqT   = (u16*)(B + 24 * MB);       // 24-56 (dead after qkv gemm)
        u16* qr    = (u16*)(B + 24 * MB);       // 8 MB
        u16* kr    = (u16*)(B + 32 * MB);       // 2 MB
        u16* vT    = (u16*)(B + 34 * MB);       // 2 MB
        float* scores = (float*)(B + 36 * MB);  // 16 MB (dead after topk24)
        float* D2  = (float*)(B + 36 * MB);     // 16 MB (after topk24)
        u64* mask  = (u64*)(B + 52 * MB);       // 4 MB
        float* C   = (float*)(B + 56 * MB);     // 24 MB (dead after reduce)
        u16* woT   = (u16*)(B + 56 * MB);       // 32 MB (after reduce)
        float* pq  = (float*)(B + 88 * MB);     // 16 MB (dead after draft)
        float* pk  = (float*)(B + 104 * MB);    // 16 MB
        float* D0  = (float*)(B + 88 * MB);
        float* D1  = (float*)(B + 104 * MB);
        float* lrq = (float*)(B + 120 * MB);
        float* lrk = lrq + 32768;
        float* cosb = lrk + 32768;
        float* sinb = cosb + 65536;
        u16* attn_bf = hs_bf;

        hipLaunchKernelGGL(init_fused_kernel, dim3(11520), dim3(256), 0, stream,
                           hs, hs_bf, cosb, sinb, mixq, mixk, lrq, lrk,
                           wq, wk, wv, wqT, wkT, wvT);
        hipLaunchKernelGGL(qkv_ppos_kernel, dim3(24960), dim3(256), 0, stream,
                           hs_bf, wqT, wkT, wvT, C, lrq, lrk, qpos, kpos, pq, pk);
        hipLaunchKernelGGL(draft0_fused_kernel, dim3(21152), dim3(256), 0, stream,
                           pq, pk, scores, C, cosb, sinb, qr, kr, vT);
        hipLaunchKernelGGL(topk_select_kernel, dim3(32, 8), dim3(256), 0, stream,
                           scores, 0, mask);
        hipLaunchKernelGGL(draft1_fused_kernel, dim3(4512), dim3(256), 0, stream,
                           pq, pk, scores, wo, woT);
        hipLaunchKernelGGL(topk_select_kernel, dim3(32, 8), dim3(256), 0, stream,
                           scores, 8, mask);
        hipLaunchKernelGGL(draft2_attn_kernel, dim3(672), dim3(256), 0, stream,
                           pq, pk, scores, qr, kr, vT, mask, attn_bf);
        hipLaunchKernelGGL(topk_select_kernel, dim3(32, 8), dim3(256), 0, stream,
                           scores, 16, mask);
        hipLaunchKernelGGL(draft_gemm_kernel, dim3(52, 8), dim3(256), 0, stream,
                           pq, pk, scores, 24);
        hipLaunchKernelGGL(topk_select_kernel, dim3(32, 8), dim3(256), 0, stream,
                           scores, 24, mask);
        hipLaunchKernelGGL(attn_mfma_kernel, dim3(16, 16), dim3(256), 0, stream,
                           qr, kr, vT, mask, attn_bf, 16);
        hipLaunchKernelGGL(gemm_wo_sk3_kernel, dim3(32, 8, 3), dim3(256), 0, stream,
                           attn_bf, woT, D0, D1, D2);
        hipLaunchKernelGGL(reduce_out3_kernel, dim3(4096), dim3(256), 0, stream,
                           D0, D1, D2, out);
    } else {
        // ---- small path: round-10 schedule verbatim (high-water ~89 MB) ----
        float* ws   = (float*)d_ws;
        float* qb   = ws;
        float* kb   = qb + 4194304;
        float* vb   = kb + 1048576;
        float* pq   = vb + 1048576;
        float* pk   = pq + 4194304;
        float* lrq  = pk + 4194304;
        float* lrk  = lrq + 32768;
        float* cosb = lrk + 32768;
        float* sinb = cosb + 65536;
        u64* mask = (u64*)(sinb + 65536);
        u16* hs_bf = (u16*)(ws + 14876672 + 1048576);
        u16* wkT   = hs_bf + 4194304;
        u16* wvT   = wkT + 4194304;
        u16* wqT   = (u16*)pq;
        u16* woT   = (u16*)pq;
        u16* qr_bf = (u16*)pq;
        u16* kr_bf = (u16*)pk;
        u16* vT_bf = (u16*)(pk + 1048576);
        u16* attn_bf = hs_bf;
        float* scores = (float*)hs_bf;

        hipLaunchKernelGGL(init_kernel, dim3(4352), dim3(256), 0, stream, hs, hs_bf, cosb, sinb);
        hipLaunchKernelGGL(transpose_qkvw_kernel, dim3(96, 64), dim3(256), 0, stream,
                           wq, wk, wv, wqT, wkT, wvT);
        hipLaunchKernelGGL(gemm_qkv_bf16_kernel, dim3(48, 8), dim3(256), 0, stream,
                           hs_bf, wqT, wkT, wvT, qb, kb, vb);
        hipLaunchKernelGGL(lr_kernel, dim3(1024), dim3(256), 0, stream, hs, mixq, mixk, lrq, lrk);
        hipLaunchKernelGGL(ppos2_kernel, dim3(32, 1536), dim3(128), 0, stream,
                           lrq, lrk, qpos, kpos, pq, pk);
        for (int h0 = 0; h0 < 32; h0 += 8) {
            hipLaunchKernelGGL(draft_gemm_kernel, dim3(52, 8), dim3(256), 0, stream,
                               pq, pk, scores, h0);
            hipLaunchKernelGGL(topk_select_kernel, dim3(32, 8), dim3(256), 0, stream,
                               scores, h0, mask);
        }
        hipLaunchKernelGGL(rope_pack2_kernel, dim3(1024, 40), dim3(128), 0, stream,
                           qb, kb, cosb, sinb, qr_bf, kr_bf);
        hipLaunchKernelGGL(transpose_bf16_kernel, dim3(16, 16), dim3(256), 0, stream,
                           vb, vT_bf, 1024, 1024);
        hipLaunchKernelGGL(attn_mfma_kernel, dim3(16, 32), dim3(256), 0, stream,
                           qr_bf, kr_bf, vT_bf, mask, attn_bf, 0);
        hipLaunchKernelGGL(transpose_bf16_kernel, dim3(64, 64), dim3(256), 0, stream,
                           wo, woT, 4096, 4096);
        hipLaunchKernelGGL(gemm_wo_bf16_kernel, dim3(32, 8), dim3(256), 0, stream,
                           attn_bf, woT, out);
    }
}

// Round 14
// 672.739 us; speedup vs baseline: 1.0753x; 1.0753x over previous
//
#include <hip/hip_runtime.h>
#include <hip/hip_bf16.h>
#include <math.h>

// Decoder_62234076119175 — round 14: revert to round-12 schedule (673 us).
// Round 13's attn/draft fusion (LDS sums, regs max) and wo split-K=3 (extra
// 16MB partial traffic) both regressed; this restores the known-good plan:
// init_fused -> qkv+ppos co-resident -> draft chunks with reduce/woT riders
// -> attn -> wo split-K=2 -> reduce. Draft/top-k stays f32 bit-identical.

typedef unsigned short u16;
typedef unsigned long long u64;
using bf16x8 = __attribute__((ext_vector_type(8))) short;
using f32x4  = __attribute__((ext_vector_type(4))) float;

#define NEGBIG -1e30f
#define QSCALE 0.08838834764831845f

__device__ __forceinline__ unsigned int fkey(float f) {
    unsigned int u = __float_as_uint(f);
    return (u & 0x80000000u) ? ~u : (u | 0x80000000u);
}

__device__ __forceinline__ u16 f2b(float f) {
    union { float f; unsigned u; } x; x.f = f;
    unsigned r = x.u + 0x7fffu + ((x.u >> 16) & 1u);  // RNE
    return (u16)(r >> 16);
}

__device__ __forceinline__ void gl_lds16(const u16* g, u16* l) {
    __builtin_amdgcn_global_load_lds(
        (__attribute__((address_space(1))) void*)(g),
        (__attribute__((address_space(3))) void*)(l), 16, 0, 0);
}

__device__ __forceinline__ void rope_table_calc(int row, int i,
    float* __restrict__ cosb, float* __restrict__ sinb)
{
    double inv = pow(10000.0, -((double)(2 * i)) / 128.0);
    double ang = (double)row * inv;
    cosb[row * 64 + i] = (float)cos(ang);
    sinb[row * 64 + i] = (float)sin(ang);
}

// ---------------- f32 [K][N] -> bf16 [N][K] transpose tile ------------------
__device__ __forceinline__ void transpose_tile(
    const float* __restrict__ in, u16* __restrict__ out, int Kdim, int N,
    int bx, int by)
{
    __shared__ u16 tile[64][66];
    int n0 = bx * 64, k0 = by * 64;
    int t = threadIdx.x;
#pragma unroll
    for (int u = 0; u < 16; ++u) {
        int e = u * 256 + t; int r = e >> 6, c = e & 63;
        tile[r][c] = f2b(in[(size_t)(k0 + r) * N + n0 + c]);
    }
    __syncthreads();
#pragma unroll
    for (int u = 0; u < 16; ++u) {
        int e = u * 256 + t; int r = e >> 6, c = e & 63;
        out[(size_t)(n0 + r) * Kdim + k0 + c] = tile[c][r];
    }
}

__global__ __launch_bounds__(256) void transpose_bf16_kernel(
    const float* __restrict__ in, u16* __restrict__ out, int Kdim, int N)
{
    transpose_tile(in, out, Kdim, N, blockIdx.x, blockIdx.y);
}

// ---------------- small-path kernels (round-10 fallback) --------------------
__global__ __launch_bounds__(256) void init_kernel(
    const float* __restrict__ hs, u16* __restrict__ hs_bf,
    float* __restrict__ cosb, float* __restrict__ sinb)
{
    int bx = blockIdx.x, t = threadIdx.x;
    if (bx < 4096) {
        int i = bx * 256 + t;
        float4 v = ((const float4*)hs)[i];
        u16 o[4] = {f2b(v.x), f2b(v.y), f2b(v.z), f2b(v.w)};
        ((uint2*)hs_bf)[i] = *(const uint2*)o;
    } else {
        rope_table_calc((bx - 4096) * 4 + (t >> 6), t & 63, cosb, sinb);
    }
}

__global__ __launch_bounds__(256) void transpose_qkvw_kernel(
    const float* __restrict__ wq, const float* __restrict__ wk, const float* __restrict__ wv,
    u16* __restrict__ wqT, u16* __restrict__ wkT, u16* __restrict__ wvT)
{
    int bx = blockIdx.x;
    const float* in; u16* outp; int N;
    if (bx < 64)      { in = wq; outp = wqT; N = 4096; }
    else if (bx < 80) { in = wk; outp = wkT; N = 1024; bx -= 64; }
    else              { in = wv; outp = wvT; N = 1024; bx -= 80; }
    transpose_tile(in, outp, 4096, N, bx, blockIdx.y);
}

__global__ __launch_bounds__(128) void rope_pack2_kernel(
    const float* __restrict__ qb, const float* __restrict__ kb,
    const float* __restrict__ cosb, const float* __restrict__ sinb,
    u16* __restrict__ qr, u16* __restrict__ kr)
{
    int s = blockIdx.x, h = blockIdx.y, d = threadIdx.x;
    const float* src; u16* dst; int W; float scale;
    if (h < 32) { src = qb; dst = qr; W = 4096; scale = QSCALE; }
    else        { h -= 32; src = kb; dst = kr; W = 1024; scale = 1.0f; }
    float x  = src[(size_t)s * W + h * 128 + d];
    float x2 = src[(size_t)s * W + h * 128 + (d ^ 64)];
    float cs = cosb[s * 64 + (d & 63)];
    float sn = sinb[s * 64 + (d & 63)];
    float rot = (d < 64) ? -x2 : x2;
    dst[((size_t)h * 1024 + s) * 128 + d] = f2b((x * cs + rot * sn) * scale);
}

__global__ __launch_bounds__(256) void lr_kernel(
    const float* __restrict__ hs, const float* __restrict__ mixq, const float* __restrict__ mixk,
    float* __restrict__ lrq, float* __restrict__ lrk)
{
    __shared__ float row[4096];
    __shared__ float part[2][32][4];
    int m = blockIdx.x, t = threadIdx.x;
#pragma unroll
    for (int u = 0; u < 4; ++u)
        ((float4*)row)[t + u * 256] = ((const float4*)(hs + (size_t)m * 4096))[t + u * 256];
    __syncthreads();
    int r = t & 31, which = (t >> 5) & 1, quarter = t >> 6;
    const float* mix = which ? mixk : mixq;
    float acc = 0.f;
    int kbase = quarter * 1024;
#pragma unroll 8
    for (int kk = 0; kk < 1024; ++kk)
        acc = fmaf(row[kbase + kk], mix[(size_t)(kbase + kk) * 32 + r], acc);
    part[which][r][quarter] = acc;
    __syncthreads();
    if (t < 64) {
        int r2 = t & 31, w2 = t >> 5;
        float s = part[w2][r2][0] + part[w2][r2][1] + part[w2][r2][2] + part[w2][r2][3];
        (w2 ? lrk : lrq)[(size_t)m * 32 + r2] = s;
    }
}

__global__ __launch_bounds__(128) void ppos2_kernel(
    const float* __restrict__ lrq, const float* __restrict__ lrk,
    const float* __restrict__ qpos, const float* __restrict__ kpos,
    float* __restrict__ pq, float* __restrict__ pk)
{
    int h = blockIdx.x, by = blockIdx.y, d = threadIdx.x;
    const float* lr; const float* pos; float* outp; int m;
    if (by < 512) { m = 512 + by; lr = lrq; pos = qpos; outp = pq; }
    else          { m = by - 512; lr = lrk; pos = kpos; outp = pk; }
    __shared__ float lrs[32];
    if (d < 32) lrs[d] = lr[(size_t)m * 32 + d];
    __syncthreads();
    const float* base = pos + ((size_t)(m * 32 + h) * 32) * 128 + d;
    float acc = 0.f;
#pragma unroll
    for (int r = 0; r < 32; ++r)
        acc = fmaf(lrs[r], base[(size_t)r * 128], acc);
    outp[((size_t)h * 1024 + m) * 128 + d] = acc;
}

// ------------- big path: fused init (conv + tables + lr + w transposes) ----
__global__ __launch_bounds__(256) void init_fused_kernel(
    const float* __restrict__ hs, u16* __restrict__ hs_bf,
    float* __restrict__ cosb, float* __restrict__ sinb,
    const float* __restrict__ mixq, const float* __restrict__ mixk,
    float* __restrict__ lrq, float* __restrict__ lrk,
    const float* __restrict__ wq, const float* __restrict__ wk, const float* __restrict__ wv,
    u16* __restrict__ wqT, u16* __restrict__ wkT, u16* __restrict__ wvT)
{
    __shared__ float row[4096];
    __shared__ float part[2][32][4];
    int bx = blockIdx.x, t = threadIdx.x;
    if (bx < 4096) {
        int i = bx * 256 + t;
        float4 v = ((const float4*)hs)[i];
        u16 o[4] = {f2b(v.x), f2b(v.y), f2b(v.z), f2b(v.w)};
        ((uint2*)hs_bf)[i] = *(const uint2*)o;
    } else if (bx < 4352) {
        rope_table_calc((bx - 4096) * 4 + (t >> 6), t & 63, cosb, sinb);
    } else if (bx < 5376) {
        int m = bx - 4352;
#pragma unroll
        for (int u = 0; u < 4; ++u)
            ((float4*)row)[t + u * 256] = ((const float4*)(hs + (size_t)m * 4096))[t + u * 256];
        __syncthreads();
        int r = t & 31, which = (t >> 5) & 1, quarter = t >> 6;
        const float* mix = which ? mixk : mixq;
        float acc = 0.f;
        int kbase = quarter * 1024;
#pragma unroll 8
        for (int kk = 0; kk < 1024; ++kk)
            acc = fmaf(row[kbase + kk], mix[(size_t)(kbase + kk) * 32 + r], acc);
        part[which][r][quarter] = acc;
        __syncthreads();
        if (t < 64) {
            int r2 = t & 31, w2 = t >> 5;
            float s = part[w2][r2][0] + part[w2][r2][1] + part[w2][r2][2] + part[w2][r2][3];
            (w2 ? lrk : lrq)[(size_t)m * 32 + r2] = s;
        }
    } else {
        int idx = bx - 5376;           // 6144 = 96 x 64
        int bxT = idx % 96, byT = idx / 96;
        const float* in; u16* outp; int N;
        if (bxT < 64)      { in = wq; outp = wqT; N = 4096; }
        else if (bxT < 80) { in = wk; outp = wkT; N = 1024; bxT -= 64; }
        else               { in = wv; outp = wvT; N = 1024; bxT -= 80; }
        transpose_tile(in, outp, 4096, N, bxT, byT);
    }
}

// ---------------- bf16 MFMA GEMM panel (m97 structure) ----------------------
__device__ __forceinline__ void gemm_bf16_panel(
    const u16* __restrict__ Ap, const u16* __restrict__ Bp,
    float* __restrict__ Cp, int Kdim, int kbase, int klen, int Cst)
{
    __shared__ u16 As[128 * 32];
    __shared__ u16 Bs[128 * 32];
    const int t = threadIdx.x;
    const int wave = t >> 6, lane = t & 63;
    const int wr = wave >> 1, wc = wave & 1;
    const int fr = lane & 15, fq = lane >> 4;

    f32x4 acc[4][4];
#pragma unroll
    for (int m = 0; m < 4; ++m)
#pragma unroll
        for (int n = 0; n < 4; ++n) acc[m][n] = 0.f;

    const int srow = 32 * wave + (lane >> 2);
    const int skc = (lane & 3) * 8;
    const u16* aS = Ap + (size_t)srow * Kdim + kbase + skc;
    const u16* bS = Bp + (size_t)srow * Kdim + kbase + skc;
    u16* aD0 = As + 1024 * wave;  u16* aD1 = aD0 + 512;
    u16* bD0 = Bs + 1024 * wave;  u16* bD1 = bD0 + 512;

    const int aoff = (wr * 64 + fr) * 32 + fq * 8;
    const int boff = (wc * 64 + fr) * 32 + fq * 8;

    for (int k0 = 0; k0 < klen; k0 += 32) {
        __syncthreads();
        gl_lds16(aS + k0, aD0);
        gl_lds16(aS + (size_t)16 * Kdim + k0, aD1);
        gl_lds16(bS + k0, bD0);
        gl_lds16(bS + (size_t)16 * Kdim + k0, bD1);
        __syncthreads();

        bf16x8 af[4], bfr[4];
#pragma unroll
        for (int m = 0; m < 4; ++m) af[m] = *(const bf16x8*)(As + aoff + m * 512);
#pragma unroll
        for (int n = 0; n < 4; ++n) bfr[n] = *(const bf16x8*)(Bs + boff + n * 512);
#pragma unroll
        for (int m = 0; m < 4; ++m)
#pragma unroll
            for (int n = 0; n < 4; ++n)
                acc[m][n] = __builtin_amdgcn_mfma_f32_16x16x32_bf16(af[m], bfr[n], acc[m][n], 0, 0, 0);
    }

    float* Cb = Cp + (size_t)(wr * 64 + fq * 4) * Cst + wc * 64 + fr;
#pragma unroll
    for (int m = 0; m < 4; ++m)
#pragma unroll
        for (int j = 0; j < 4; ++j)
#pragma unroll
            for (int n = 0; n < 4; ++n)
                Cb[(size_t)(m * 16 + j) * Cst + n * 16] = acc[m][n][j];
}

// small-path GEMM wrappers
__global__ __launch_bounds__(256) void gemm_qkv_bf16_kernel(
    const u16* __restrict__ hs_bf, const u16* __restrict__ wqT,
    const u16* __restrict__ wkT, const u16* __restrict__ wvT,
    float* __restrict__ q, float* __restrict__ k, float* __restrict__ v)
{
    int bn = blockIdx.x, bm = blockIdx.y;
    const u16* Bsel; float* Csel; int Ncols;
    if (bn < 32)      { Bsel = wqT; Csel = q; Ncols = 4096; }
    else if (bn < 40) { Bsel = wkT; Csel = k; Ncols = 1024; bn -= 32; }
    else              { Bsel = wvT; Csel = v; Ncols = 1024; bn -= 40; }
    gemm_bf16_panel(hs_bf + (size_t)bm * 128 * 4096, Bsel + (size_t)bn * 128 * 4096,
                    Csel + (size_t)bm * 128 * Ncols + bn * 128, 4096, 0, 4096, Ncols);
}

__global__ __launch_bounds__(256) void gemm_wo_bf16_kernel(
    const u16* __restrict__ attn_bf, const u16* __restrict__ woT, float* __restrict__ out)
{
    int bn = blockIdx.x, bm = blockIdx.y;
    gemm_bf16_panel(attn_bf + (size_t)bm * 128 * 4096, woT + (size_t)bn * 128 * 4096,
                    out + (size_t)bm * 128 * 4096 + bn * 128, 4096, 0, 4096, 4096);
}

// ------------- big path: mega kernel — qkv GEMM + ppos co-resident ----------
__global__ __launch_bounds__(256) void qkv_ppos_kernel(
    const u16* __restrict__ hs_bf, const u16* __restrict__ wqT,
    const u16* __restrict__ wkT, const u16* __restrict__ wvT,
    float* __restrict__ C,
    const float* __restrict__ lrq, const float* __restrict__ lrk,
    const float* __restrict__ qpos, const float* __restrict__ kpos,
    float* __restrict__ pq, float* __restrict__ pk)
{
    int bx = blockIdx.x, t = threadIdx.x;
    if (bx < 384) {
        int bn = bx % 48, bm = bx / 48;
        const u16* Bsel; int bnrow;
        if (bn < 32)      { Bsel = wqT; bnrow = bn; }
        else if (bn < 40) { Bsel = wkT; bnrow = bn - 32; }
        else              { Bsel = wvT; bnrow = bn - 40; }
        gemm_bf16_panel(hs_bf + (size_t)bm * 128 * 4096, Bsel + (size_t)bnrow * 128 * 4096,
                        C + (size_t)bm * 128 * 6144 + bn * 128, 4096, 0, 4096, 6144);
    } else {
        int idx = bx - 384;               // 24576 blocks: 768 row-pairs x 32 h
        int bp = idx >> 5, h = idx & 31;
        int sub = t >> 7, d = t & 127;
        int by = bp * 2 + sub;
        const float* lr; const float* pos; float* outp; int m;
        if (by < 512) { m = 512 + by; lr = lrq; pos = qpos; outp = pq; }
        else          { m = by - 512; lr = lrk; pos = kpos; outp = pk; }
        __shared__ float lrs[2][32];
        if (d < 32) lrs[sub][d] = lr[(size_t)m * 32 + d];
        __syncthreads();
        const float* base = pos + ((size_t)(m * 32 + h) * 32) * 128 + d;
        float acc = 0.f;
#pragma unroll
        for (int r = 0; r < 32; ++r)
            acc = fmaf(lrs[sub][r], base[(size_t)r * 128], acc);
        outp[((size_t)h * 1024 + m) * 128 + d] = acc;
    }
}

// ------------- reduce: single-C rope pack (q,k) item ------------------------
__device__ __forceinline__ void reduce_rope_item(
    const float* __restrict__ C,
    const float* __restrict__ cosb, const float* __restrict__ sinb,
    u16* __restrict__ qr, u16* __restrict__ kr, int bx)
{
    int t = threadIdx.x;
    int sp = bx & 511, h40 = bx >> 9;
    int s = sp * 2 + (t >> 7), d = t & 127;
    int col; u16* dst; float scale;
    if (h40 < 32) { col = h40 * 128 + d; dst = qr + ((size_t)h40 * 1024 + s) * 128 + d; scale = QSCALE; }
    else { col = 4096 + (h40 - 32) * 128 + d; dst = kr + ((size_t)(h40 - 32) * 1024 + s) * 128 + d; scale = 1.0f; }
    int colp = col ^ 64;
    float x  = C[(size_t)s * 6144 + col];
    float x2 = C[(size_t)s * 6144 + colp];
    float cs = cosb[s * 64 + (d & 63)];
    float sn = sinb[s * 64 + (d & 63)];
    float rot = (d < 64) ? -x2 : x2;
    *dst = f2b((x * cs + rot * sn) * scale);
}

__device__ __forceinline__ void v_transpose_dev(
    const float* __restrict__ C, u16* __restrict__ vT, int idx)
{
    __shared__ u16 vtile[64][66];
    int bxT = idx & 15, byT = idx >> 4;
    int n0 = bxT * 64, k0 = byT * 64;
    int t = threadIdx.x;
#pragma unroll
    for (int u = 0; u < 16; ++u) {
        int e = u * 256 + t; int r = e >> 6, c = e & 63;
        vtile[r][c] = f2b(C[(size_t)(k0 + r) * 6144 + 5120 + n0 + c]);
    }
    __syncthreads();
#pragma unroll
    for (int u = 0; u < 16; ++u) {
        int e = u * 256 + t; int r = e >> 6, c = e & 63;
        vT[(size_t)(n0 + r) * 1024 + k0 + c] = vtile[c][r];
    }
}

// ---------------- draft tile compute (f32 exact, 128x64) --------------------
__device__ __forceinline__ void draft_tile_compute(
    const float* __restrict__ pq, const float* __restrict__ pk,
    float* __restrict__ scores, int h0, int idx, int hh)
{
    int bm, bc;
    if (idx < 10)      { bm = 4; bc = idx; }
    else if (idx < 22) { bm = 5; bc = idx - 10; }
    else if (idx < 36) { bm = 6; bc = idx - 22; }
    else               { bm = 7; bc = idx - 36; }

    const float* A  = pq + ((size_t)(h0 + hh) * 1024 + bm * 128) * 128;
    const float* BT = pk + ((size_t)(h0 + hh) * 1024 + bc * 64) * 128;
    float* Cs = scores + ((size_t)hh * 512 + (bm - 4) * 128) * 1024 + bc * 64;

    __shared__ float As[8][128];
    __shared__ float Bs[8][64];
    const int t = threadIdx.x;
    const int tx = t & 15, ty = (t >> 4) & 15;

    float acc[8][4];
#pragma unroll
    for (int u = 0; u < 8; ++u)
#pragma unroll
        for (int w = 0; w < 4; ++w) acc[u][w] = 0.f;

    const int ai = t >> 1, ah = (t & 1) * 4;
    const int bi = t >> 2, bh = (t & 3) * 2;
    const float* Ap = A + (size_t)ai * 128 + ah;
    const float* Bp = BT + (size_t)bi * 128 + bh;

    for (int k0 = 0; k0 < 128; k0 += 8) {
        float4 av = *(const float4*)(Ap + k0);
        float2 bv = *(const float2*)(Bp + k0);
        __syncthreads();
        As[ah + 0][ai] = av.x; As[ah + 1][ai] = av.y;
        As[ah + 2][ai] = av.z; As[ah + 3][ai] = av.w;
        Bs[bh][bi] = bv.x; Bs[bh + 1][bi] = bv.y;
        __syncthreads();
#pragma unroll
        for (int kk = 0; kk < 8; ++kk) {
            float4 a0 = *(const float4*)(&As[kk][ty * 4]);
            float4 a1 = *(const float4*)(&As[kk][64 + ty * 4]);
            float4 b0 = *(const float4*)(&Bs[kk][tx * 4]);
            float aa[8] = {a0.x, a0.y, a0.z, a0.w, a1.x, a1.y, a1.z, a1.w};
#pragma unroll
            for (int u = 0; u < 8; ++u) {
                acc[u][0] = fmaf(aa[u], b0.x, acc[u][0]);
                acc[u][1] = fmaf(aa[u], b0.y, acc[u][1]);
                acc[u][2] = fmaf(aa[u], b0.z, acc[u][2]);
                acc[u][3] = fmaf(aa[u], b0.w, acc[u][3]);
            }
        }
    }
#pragma unroll
    for (int u = 0; u < 8; ++u) {
        int row = (u < 4) ? (ty * 4 + u) : (64 + ty * 4 + (u - 4));
        *(float4*)(Cs + (size_t)row * 1024 + tx * 4)
            = make_float4(acc[u][0], acc[u][1], acc[u][2], acc[u][3]);
    }
}

__global__ __launch_bounds__(256) void draft_gemm_kernel(
    const float* __restrict__ pq, const float* __restrict__ pk,
    float* __restrict__ scores, int h0)
{
    draft_tile_compute(pq, pk, scores, h0, blockIdx.x, blockIdx.y);
}

// chunk 0: draft(h0=0) + reduce_rope + v-transpose riding along
__global__ __launch_bounds__(256) void draft0_fused_kernel(
    const float* __restrict__ pq, const float* __restrict__ pk,
    float* __restrict__ scores, const float* __restrict__ C,
    const float* __restrict__ cosb, const float* __restrict__ sinb,
    u16* __restrict__ qr, u16* __restrict__ kr, u16* __restrict__ vT)
{
    int bx = blockIdx.x;
    if (bx < 416) draft_tile_compute(pq, pk, scores, 0, bx % 52, bx / 52);
    else if (bx < 416 + 20480) reduce_rope_item(C, cosb, sinb, qr, kr, bx - 416);
    else v_transpose_dev(C, vT, bx - 416 - 20480);
}

// chunk 1: draft(h0=8) + wo transpose riding along
__global__ __launch_bounds__(256) void draft1_fused_kernel(
    const float* __restrict__ pq, const float* __restrict__ pk,
    float* __restrict__ scores, const float* __restrict__ wo, u16* __restrict__ woT)
{
    int bx = blockIdx.x;
    if (bx < 416) draft_tile_compute(pq, pk, scores, 8, bx % 52, bx / 52);
    else { int i = bx - 416; transpose_tile(wo, woT, 4096, 4096, i & 63, i >> 6); }
}

// ---------------- exact top-512 radix select (q>=512), float4 reads --------
__global__ __launch_bounds__(256) void topk_select_kernel(
    const float* __restrict__ scores, int h0,
    unsigned long long* __restrict__ mask)
{
    int qt = blockIdx.x, hh = blockIdx.y;
    int h = h0 + hh;
    int t = threadIdx.x;
    const int i = t >> 4, jj = t & 15;
    const int lrow = qt * 16 + i;
    const int qrow = 512 + lrow;

    const float* src = scores + ((size_t)hh * 512 + lrow) * 1024;

    unsigned int vals[64];
#pragma unroll
    for (int g = 0; g < 16; ++g) {
        float4 v = *(const float4*)(src + g * 64 + jj * 4);
        int col = g * 64 + jj * 4;
        vals[g * 4 + 0] = fkey((col + 0) <= qrow ? v.x : NEGBIG);
        vals[g * 4 + 1] = fkey((col + 1) <= qrow ? v.y : NEGBIG);
        vals[g * 4 + 2] = fkey((col + 2) <= qrow ? v.z : NEGBIG);
        vals[g * 4 + 3] = fkey((col + 3) <= qrow ? v.w : NEGBIG);
    }

    unsigned int p = 0u;
    int kth = 512;
    for (int b = 31; b >= 0; --b) {
        unsigned int bit = 1u << b;
        unsigned int himask = (b == 31) ? 0u : (0xFFFFFFFFu << (b + 1));
        int cnt = 0;
#pragma unroll
        for (int n = 0; n < 64; ++n)
            cnt += (int)((((vals[n] ^ p) & himask) == 0u) && ((vals[n] & bit) != 0u));
        cnt += __shfl_xor(cnt, 1);
        cnt += __shfl_xor(cnt, 2);
        cnt += __shfl_xor(cnt, 4);
        cnt += __shfl_xor(cnt, 8);
        if (cnt >= kth) p |= bit; else kth -= cnt;
    }

    unsigned long long wpart[16];
#pragma unroll
    for (int w = 0; w < 16; ++w) wpart[w] = 0ull;
#pragma unroll
    for (int g = 0; g < 16; ++g)
#pragma unroll
        for (int e = 0; e < 4; ++e)
            wpart[g] |= ((unsigned long long)(vals[g * 4 + e] >= p)) << (4 * jj + e);
#pragma unroll
    for (int s = 1; s < 16; s <<= 1) {
#pragma unroll
        for (int w = 0; w < 16; ++w)
            wpart[w] |= __shfl_xor(wpart[w], s);
    }
    mask[((size_t)h * 1024 + qrow) * 16 + jj] = wpart[jj];
}

// big path: split-K=2 wo GEMM
__global__ __launch_bounds__(256) void gemm_wo_sk_kernel(
    const u16* __restrict__ attn_bf, const u16* __restrict__ woT,
    float* __restrict__ D0, float* __restrict__ D1)
{
    int bn = blockIdx.x, bm = blockIdx.y, g = blockIdx.z;
    float* C = g ? D1 : D0;
    gemm_bf16_panel(attn_bf + (size_t)bm * 128 * 4096, woT + (size_t)bn * 128 * 4096,
                    C + (size_t)bm * 128 * 4096 + bn * 128, 4096, g * 2048, 2048, 4096);
}

__global__ __launch_bounds__(256) void reduce_out_kernel(
    const float* __restrict__ D0, const float* __restrict__ D1, float* __restrict__ out)
{
    int i = blockIdx.x * 256 + threadIdx.x;
    float4 a = ((const float4*)D0)[i];
    float4 b = ((const float4*)D1)[i];
    ((float4*)out)[i] = make_float4(a.x + b.x, a.y + b.y, a.z + b.z, a.w + b.w);
}

// ---------------- MFMA flash attention, swapped QK^T, KVBLK=64 -------------
#define ATTN_KP 136
#define ATTN_VP 72

__global__ __launch_bounds__(256) void attn_mfma_kernel(
    const u16* __restrict__ qr, const u16* __restrict__ kr,
    const u16* __restrict__ vT,
    const unsigned long long* __restrict__ mask,
    u16* __restrict__ attn)
{
    int bx = blockIdx.x;
    int qt = (bx & 1) ? (bx >> 1) : (15 - (bx >> 1));
    int h = blockIdx.y;
    int kvh = h >> 2;
    int q0 = qt * 64;
    int t = threadIdx.x;
    int wave = t >> 6, lane = t & 63;
    int fr = lane & 15, fq = lane >> 4;
    int qrow = q0 + wave * 16 + fr;

    __shared__ u16 Ks[64 * ATTN_KP];
    __shared__ u16 Vs[128 * ATTN_VP];

    bf16x8 qf[4];
    const u16* qbase = qr + ((size_t)h * 1024 + qrow) * 128 + fq * 8;
#pragma unroll
    for (int kc = 0; kc < 4; ++kc)
        qf[kc] = *(const bf16x8*)(qbase + kc * 32);

    float m_run = -3.0e38f, l_run = 0.f;
    f32x4 accO[8];
#pragma unroll
    for (int m2 = 0; m2 < 8; ++m2) accO[m2] = 0.f;

    const unsigned long long* mrow = mask + ((size_t)h * 1024 + qrow) * 16;
    const bool use_mask = (qrow >= 512);
    const u16* kgh = kr + (size_t)kvh * 1024 * 128;
    const u16* vgh = vT + (size_t)kvh * 128 * 1024;

    int ntiles = qt + 1;
    for (int c = 0; c < ntiles; ++c) {
        int kv0 = c * 64;
        __syncthreads();
#pragma unroll
        for (int u = 0; u < 4; ++u) {
            int e = t + u * 256;
            int row = e >> 4, bc2 = (e & 15) * 8;
            uint4 d4 = *(const uint4*)(kgh + ((size_t)(kv0 + row)) * 128 + bc2);
            *(uint4*)(&Ks[row * ATTN_KP + bc2]) = d4;
        }
#pragma unroll
        for (int u = 0; u < 4; ++u) {
            int e = t + u * 256;
            int row = e >> 3, bc2 = (e & 7) * 8;
            uint4 d4 = *(const uint4*)(vgh + (size_t)row * 1024 + kv0 + bc2);
            *(uint4*)(&Vs[row * ATTN_VP + bc2]) = d4;
        }
        __syncthreads();

        f32x4 accS[4];
        accS[0] = 0.f; accS[1] = 0.f; accS[2] = 0.f; accS[3] = 0.f;
#pragma unroll
        for (int t2 = 0; t2 < 4; ++t2)
#pragma unroll
            for (int kc = 0; kc < 4; ++kc) {
                bf16x8 kf = *(const bf16x8*)(&Ks[(t2 * 16 + fr) * ATTN_KP + kc * 32 + fq * 8]);
                accS[t2] = __builtin_amdgcn_mfma_f32_16x16x32_bf16(kf, qf[kc], accS[t2], 0, 0, 0);
            }

        unsigned long long mw = use_mask ? mrow[c] : ~0ull;
        float p[4][4];
        float tmax = -3.0e38f;
#pragma unroll
        for (int t2 = 0; t2 < 4; ++t2)
#pragma unroll
            for (int j = 0; j < 4; ++j) {
                int kvi = (t2 << 4) + (fq << 2) + j;
                bool ok = ((mw >> kvi) & 1ull) && (kv0 + kvi <= qrow);
                float s = ok ? accS[t2][j] : -3.0e38f;
                p[t2][j] = s;
                tmax = fmaxf(tmax, s);
            }
        tmax = fmaxf(tmax, __shfl_xor(tmax, 16));
        tmax = fmaxf(tmax, __shfl_xor(tmax, 32));
        float m_new = fmaxf(m_run, tmax);
        float sf = __expf(m_run - m_new);
        float psum = 0.f;
#pragma unroll
        for (int t2 = 0; t2 < 4; ++t2)
#pragma unroll
            for (int j = 0; j < 4; ++j) {
                float e = (p[t2][j] > -1.0e38f) ? __expf(p[t2][j] - m_new) : 0.f;
                p[t2][j] = e;
                psum += e;
            }
        psum += __shfl_xor(psum, 16);
        psum += __shfl_xor(psum, 32);
        l_run = l_run * sf + psum;
        m_run = m_new;

#pragma unroll
        for (int m2 = 0; m2 < 8; ++m2) accO[m2] *= sf;

        union { uint4 u; bf16x8 b; } pc[2];
        int srcA = fr + ((fq & 1) << 5);
        int srcB = srcA + 16;
        bool hi = (fq & 2) != 0;
#pragma unroll
        for (int half = 0; half < 2; ++half) {
            unsigned W0, W1, W2, W3;
            asm("v_cvt_pk_bf16_f32 %0, %1, %2" : "=v"(W0) : "v"(p[2 * half][0]),     "v"(p[2 * half][1]));
            asm("v_cvt_pk_bf16_f32 %0, %1, %2" : "=v"(W1) : "v"(p[2 * half][2]),     "v"(p[2 * half][3]));
            asm("v_cvt_pk_bf16_f32 %0, %1, %2" : "=v"(W2) : "v"(p[2 * half + 1][0]), "v"(p[2 * half + 1][1]));
            asm("v_cvt_pk_bf16_f32 %0, %1, %2" : "=v"(W3) : "v"(p[2 * half + 1][2]), "v"(p[2 * half + 1][3]));
            unsigned a0 = __shfl(W0, srcA), a1 = __shfl(W1, srcA);
            unsigned a2 = __shfl(W2, srcA), a3 = __shfl(W3, srcA);
            unsigned b0 = __shfl(W0, srcB), b1 = __shfl(W1, srcB);
            unsigned b2 = __shfl(W2, srcB), b3 = __shfl(W3, srcB);
            pc[half].u.x = hi ? a2 : a0;
            pc[half].u.y = hi ? a3 : a1;
            pc[half].u.z = hi ? b2 : b0;
            pc[half].u.w = hi ? b3 : b1;
        }

#pragma unroll
        for (int m2 = 0; m2 < 8; ++m2) {
            bf16x8 vf0 = *(const bf16x8*)(&Vs[(m2 * 16 + fr) * ATTN_VP + fq * 8]);
            accO[m2] = __builtin_amdgcn_mfma_f32_16x16x32_bf16(vf0, pc[0].b, accO[m2], 0, 0, 0);
            bf16x8 vf1 = *(const bf16x8*)(&Vs[(m2 * 16 + fr) * ATTN_VP + 32 + fq * 8]);
            accO[m2] = __builtin_amdgcn_mfma_f32_16x16x32_bf16(vf1, pc[1].b, accO[m2], 0, 0, 0);
        }
    }

    float il = 1.0f / l_run;
    u16* obase = attn + (size_t)qrow * 4096 + h * 128 + fq * 4;
#pragma unroll
    for (int m2 = 0; m2 < 8; ++m2) {
        uint2 st;
        st.x = (unsigned)f2b(accO[m2][0] * il) | ((unsigned)f2b(accO[m2][1] * il) << 16);
        st.y = (unsigned)f2b(accO[m2][2] * il) | ((unsigned)f2b(accO[m2][3] * il) << 16);
        *(uint2*)(obase + m2 * 16) = st;
    }
}

extern "C" void kernel_launch(void* const* d_in, const int* in_sizes, int n_in,
                              void* d_out, int out_size, void* d_ws, size_t ws_size,
                              hipStream_t stream)
{
    (void)in_sizes; (void)n_in; (void)out_size;
    const float* hs   = (const float*)d_in[0];
    const float* wq   = (const float*)d_in[1];
    const float* wk   = (const float*)d_in[2];
    const float* wv   = (const float*)d_in[3];
    const float* wo   = (const float*)d_in[4];
    const float* mixq = (const float*)d_in[5];
    const float* mixk = (const float*)d_in[6];
    const float* qpos = (const float*)d_in[7];
    const float* kpos = (const float*)d_in[8];
    float* out = (float*)d_out;
    char* B = (char*)d_ws;
    const size_t MB = 1ull << 20;

    if (ws_size >= 123 * MB) {
        // ---- big path, compact layout (high-water ~121 MB) ----
        u16* hs_bf = (u16*)(B);                 // 0-8, later attn_bf
        u16* wkT   = (u16*)(B + 8 * MB);
        u16* wvT   = (u16*)(B + 16 * MB);
        u16* wqT   = (u16*)(B + 24 * MB);       // 24-56 (dead after qkv gemm)
        u16* qr    = (u16*)(B + 24 * MB);       // 8 MB
        u16* kr    = (u16*)(B + 32 * MB);       // 2 MB
        u16* vT    = (u16*)(B + 34 * MB);       // 2 MB
        float* scores = (float*)(B + 36 * MB);  // 16 MB (8-head chunks)
        u64* mask  = (u64*)(B + 52 * MB);       // 4 MB (rows q>=512 used)
        float* C   = (float*)(B + 56 * MB);     // 24 MB (dead after reduce)
        u16* woT   = (u16*)(B + 56 * MB);       // 32 MB (after reduce)
        float* pq  = (float*)(B + 88 * MB);     // 16 MB (dead after draft)
        float* pk  = (float*)(B + 104 * MB);    // 16 MB
        float* D0  = (float*)(B + 88 * MB);     // after draft
        float* D1  = (float*)(B + 104 * MB);
        float* lrq = (float*)(B + 120 * MB);    // 128 KB
        float* lrk = lrq + 32768;
        float* cosb = lrk + 32768;
        float* sinb = cosb + 65536;             // ends ~120.75 MB
        u16* attn_bf = hs_bf;

        hipLaunchKernelGGL(init_fused_kernel, dim3(11520), dim3(256), 0, stream,
                           hs, hs_bf, cosb, sinb, mixq, mixk, lrq, lrk,
                           wq, wk, wv, wqT, wkT, wvT);
        hipLaunchKernelGGL(qkv_ppos_kernel, dim3(24960), dim3(256), 0, stream,
                           hs_bf, wqT, wkT, wvT, C, lrq, lrk, qpos, kpos, pq, pk);
        hipLaunchKernelGGL(draft0_fused_kernel, dim3(21152), dim3(256), 0, stream,
                           pq, pk, scores, C, cosb, sinb, qr, kr, vT);
        hipLaunchKernelGGL(topk_select_kernel, dim3(32, 8), dim3(256), 0, stream,
                           scores, 0, mask);
        hipLaunchKernelGGL(draft1_fused_kernel, dim3(4512), dim3(256), 0, stream,
                           pq, pk, scores, wo, woT);
        hipLaunchKernelGGL(topk_select_kernel, dim3(32, 8), dim3(256), 0, stream,
                           scores, 8, mask);
        hipLaunchKernelGGL(draft_gemm_kernel, dim3(52, 8), dim3(256), 0, stream,
                           pq, pk, scores, 16);
        hipLaunchKernelGGL(topk_select_kernel, dim3(32, 8), dim3(256), 0, stream,
                           scores, 16, mask);
        hipLaunchKernelGGL(draft_gemm_kernel, dim3(52, 8), dim3(256), 0, stream,
                           pq, pk, scores, 24);
        hipLaunchKernelGGL(topk_select_kernel, dim3(32, 8), dim3(256), 0, stream,
                           scores, 24, mask);
        hipLaunchKernelGGL(attn_mfma_kernel, dim3(16, 32), dim3(256), 0, stream,
                           qr, kr, vT, mask, attn_bf);
        hipLaunchKernelGGL(gemm_wo_sk_kernel, dim3(32, 8, 2), dim3(256), 0, stream,
                           attn_bf, woT, D0, D1);
        hipLaunchKernelGGL(reduce_out_kernel, dim3(4096), dim3(256), 0, stream,
                           D0, D1, out);
    } else {
        // ---- small path: round-10 schedule verbatim (high-water ~89 MB) ----
        float* ws   = (float*)d_ws;
        float* qb   = ws;
        float* kb   = qb + 4194304;
        float* vb   = kb + 1048576;
        float* pq   = vb + 1048576;
        float* pk   = pq + 4194304;
        float* lrq  = pk + 4194304;
        float* lrk  = lrq + 32768;
        float* cosb = lrk + 32768;
        float* sinb = cosb + 65536;
        u64* mask = (u64*)(sinb + 65536);
        u16* hs_bf = (u16*)(ws + 14876672 + 1048576);
        u16* wkT   = hs_bf + 4194304;
        u16* wvT   = wkT + 4194304;
        u16* wqT   = (u16*)pq;
        u16* woT   = (u16*)pq;
        u16* qr_bf = (u16*)pq;
        u16* kr_bf = (u16*)pk;
        u16* vT_bf = (u16*)(pk + 1048576);
        u16* attn_bf = hs_bf;
        float* scores = (float*)hs_bf;

        hipLaunchKernelGGL(init_kernel, dim3(4352), dim3(256), 0, stream, hs, hs_bf, cosb, sinb);
        hipLaunchKernelGGL(transpose_qkvw_kernel, dim3(96, 64), dim3(256), 0, stream,
                           wq, wk, wv, wqT, wkT, wvT);
        hipLaunchKernelGGL(gemm_qkv_bf16_kernel, dim3(48, 8), dim3(256), 0, stream,
                           hs_bf, wqT, wkT, wvT, qb, kb, vb);
        hipLaunchKernelGGL(lr_kernel, dim3(1024), dim3(256), 0, stream, hs, mixq, mixk, lrq, lrk);
        hipLaunchKernelGGL(ppos2_kernel, dim3(32, 1536), dim3(128), 0, stream,
                           lrq, lrk, qpos, kpos, pq, pk);
        for (int h0 = 0; h0 < 32; h0 += 8) {
            hipLaunchKernelGGL(draft_gemm_kernel, dim3(52, 8), dim3(256), 0, stream,
                               pq, pk, scores, h0);
            hipLaunchKernelGGL(topk_select_kernel, dim3(32, 8), dim3(256), 0, stream,
                               scores, h0, mask);
        }
        hipLaunchKernelGGL(rope_pack2_kernel, dim3(1024, 40), dim3(128), 0, stream,
                           qb, kb, cosb, sinb, qr_bf, kr_bf);
        hipLaunchKernelGGL(transpose_bf16_kernel, dim3(16, 16), dim3(256), 0, stream,
                           vb, vT_bf, 1024, 1024);
        hipLaunchKernelGGL(attn_mfma_kernel, dim3(16, 32), dim3(256), 0, stream,
                           qr_bf, kr_bf, vT_bf, mask, attn_bf);
        hipLaunchKernelGGL(transpose_bf16_kernel, dim3(64, 64), dim3(256), 0, stream,
                           wo, woT, 4096, 4096);
        hipLaunchKernelGGL(gemm_wo_bf16_kernel, dim3(32, 8), dim3(256), 0, stream,
                           attn_bf, woT, out);
    }
}